// Round 18
// baseline (380.715 us; speedup 1.0000x reference)
//
#include <hip/hip_runtime.h>

typedef _Float16 f16;
typedef _Float16 f16x2 __attribute__((ext_vector_type(2)));
typedef _Float16 f16x8 __attribute__((ext_vector_type(8)));
typedef float f32x4 __attribute__((ext_vector_type(4)));

namespace {

constexpr int kC = 16, kN = 8192, kH = 181, kOut = 3;
constexpr int kMB = 64;            // points per block = 4 wave-owned 16-row tiles
constexpr int kKpad = 384;         // 12 ksteps * 32
constexpr int kNT = 48;            // tiles of 16 output-comps (4 neurons each)
constexpr int kKS = 12;            // k-steps of 32
constexpr int kRowB = 784;         // 768 data bytes + 16B pad (bank spread)
constexpr float kOmega = 30.f, kS2 = 100.f;

constexpr size_t kWLayerStride = (size_t)kNT * kKS * 64 * 8;  // f16 per (c,layer)
constexpr size_t kWfOff = kWLayerStride * kC * 2;             // f16 elems
constexpr size_t kWfStride = (size_t)kKS * 64 * 8;
constexpr size_t kW0Off = kWfOff + (size_t)kC * kWfStride;    // layer-0 frags
constexpr size_t kW0Stride = (size_t)kNT * 64 * 8;            // per c

__device__ __forceinline__ int xadr(int row, int colb) { return row * kRowB + colb; }

// ---- prep: pack hidden-layer complex weights into fp16 fragment order
// ws[c][L][nt][ks][lane][8]; K rows 2i/2i+1 = (x_re,x_im), 16-wide tile dim =
// 4o+comp. Used as the MFMA *A* operand (C^T formulation).
__global__ __launch_bounds__(768) void prep_hidden(
    const int* __restrict__ model_idx,
    const float* __restrict__ W1a, const float* __restrict__ W1b,
    const float* __restrict__ W2a, const float* __restrict__ W2b,
    f16* __restrict__ ws)
{
  __shared__ float s[kH][2][4][2];   // [i][branch][o_sub][reim]
  const int bid = blockIdx.x;
  const int c  = bid / (2 * kNT);
  const int L  = (bid / kNT) % 2;
  const int nt = bid % kNT;
  const int m  = model_idx[c];
  const float* Wa = (L == 0 ? W1a : W2a) + (size_t)m * kH * kH * 2;
  const float* Wb = (L == 0 ? W1b : W2b) + (size_t)m * kH * kH * 2;
  const int t = threadIdx.x;
  if (t < 2 * kH) {
    const int i = t >> 1, br = t & 1;
    const float* src = (br ? Wb : Wa) + ((size_t)i * kH + nt * 4) * 2;
#pragma unroll
    for (int e = 0; e < 8; ++e) {
      const int osub = e >> 1, reim = e & 1;
      s[i][br][osub][reim] = (nt * 4 + osub < kH) ? src[osub * 2 + reim] : 0.f;
    }
  }
  __syncthreads();
  const int ks = t >> 6, lane = t & 63;
  const int kg = lane >> 4, l15 = lane & 15;
  const int osub = l15 >> 2, comp = l15 & 3, br = comp >> 1;
  const int o = nt * 4 + osub;
  f16x8 v;
#pragma unroll
  for (int j = 0; j < 8; ++j) {
    const int k = ks * 32 + kg * 8 + j;
    float f = 0.f;
    if (k < 2 * kH && o < kH) {
      const int i = k >> 1, kodd = k & 1;
      const int reim = kodd ? (1 - (comp & 1)) : (comp & 1);
      f = s[i][br][osub][reim];
      if (kodd && !(comp & 1)) f = -f;   // -w_im for real-output rows
    }
    v[j] = (f16)f;
  }
  *(f16x8*)&ws[(((size_t)(c * 2 + L) * kNT + nt) * kKS + ks) * 512 + lane * 8] = v;
}

// ---- prep: final layer (real part): col j<3, k=2i -> wf_re, 2i+1 -> -wf_im
__global__ __launch_bounds__(768) void prep_final(
    const int* __restrict__ model_idx, const float* __restrict__ Wf,
    f16* __restrict__ ws)
{
  const int c = blockIdx.x;
  const int m = model_idx[c];
  const int t = threadIdx.x;
  const int ks = t >> 6, lane = t & 63;
  const int kg = lane >> 4, col = lane & 15;
  f16x8 v;
#pragma unroll
  for (int j = 0; j < 8; ++j) {
    const int k = ks * 32 + kg * 8 + j;
    float f = 0.f;
    if (k < 2 * kH && col < kOut) {
      const int i = k >> 1;
      const float* p = &Wf[(((size_t)m * kH + i) * kOut + col) * 2];
      f = (k & 1) ? -p[1] : p[0];
    }
    v[j] = (f16)f;
  }
  *(f16x8*)&ws[kWfOff + ((size_t)c * kKS + ks) * 512 + lane * 8] = v;
}

// ---- prep: layer-0 A-frags. One K=32 tile, only k=0,1 valid.
// comp rows: (W0a[k][o], 0, W0b[k][o], 0) -> acc = (la, 0, lb, 0).
__global__ __launch_bounds__(256) void prep_l0(
    const int* __restrict__ model_idx,
    const float* __restrict__ W0a, const float* __restrict__ W0b,
    f16* __restrict__ ws)
{
  const int c = blockIdx.x;
  const int m = model_idx[c];
#pragma unroll 1
  for (int it = 0; it < 12; ++it) {
    const int slot = it * 256 + threadIdx.x;   // 48 nt x 64 lanes
    const int nt = slot >> 6, lane = slot & 63;
    const int kg = lane >> 4, l15 = lane & 15;
    const int osub = l15 >> 2, comp = l15 & 3;
    const int o = nt * 4 + osub;
    f16x8 v = {};
    if (kg == 0 && o < kH && (comp & 1) == 0) {
#pragma unroll
      for (int k = 0; k < 2; ++k) {
        const float f = (comp == 0) ? W0a[(m * 2 + k) * kH + o]
                                    : W0b[(m * 2 + k) * kH + o];
        v[k] = (f16)f;
      }
    }
    *(f16x8*)&ws[kW0Off + (size_t)c * kW0Stride + (size_t)slot * 8] = v;
  }
}

// ---- one hidden layer, IN PLACE, C^T, PER-WAVE ROW OWNERSHIP.
// Wave w owns rows 16w..16w+15: B-hold is only ITS 12 frags (48 regs), and it
// iterates ALL 48 nt. All 4 waves stream the SAME A-address sequence ->
// each A-frag: 1 L2 fill + 3 L1 hits (32KB L1 covers the <=2-nt drift bounded
// by a __syncthreads every 2 nt). Reads/writes touch only own rows -> no
// capture barrier, race-free in-place. A-stream double-buffered (r17 schedule:
// A0/A1 6+6, sched_barrier-pinned). Regs ~130 -> 3 waves/SIMD (LDS 49KB -> 3
// blocks/CU).
__device__ __forceinline__ void hidden_layer(
    char* __restrict__ X, const f16x8* __restrict__ wl,
    const float* __restrict__ ba, const float* __restrict__ bb,
    int w, int lane)
{
  const int kg = lane >> 4, l15 = lane & 15;
  const int row = 16 * w + l15;
  f16x8 B[kKS];
#pragma unroll
  for (int ks = 0; ks < kKS; ++ks)
    B[ks] = *(const f16x8*)(X + xadr(row, ks * 64 + kg * 16));
  // no barrier: only this wave reads/writes its rows

  f16x8 A0[6], A1[6];
  {  // prologue: first half-batch of nt=0
    const f16x8* ap0 = wl + lane;
#pragma unroll
    for (int j = 0; j < 6; ++j) A0[j] = ap0[j * 64];
  }

#pragma unroll 1
  for (int nt = 0; nt < kNT; ++nt) {
    const int q = nt * 4 + kg;           // this lane's neuron
    const f16x8* ap = wl + (size_t)nt * (kKS * 64) + lane;
    float br_ = 0.f, bi_ = 0.f, cr_ = 0.f, ci_ = 0.f;
    if (q < kH) {
      const float2 bav = *(const float2*)&ba[q * 2];
      const float2 bbv = *(const float2*)&bb[q * 2];
      br_ = bav.x; bi_ = bav.y; cr_ = bbv.x; ci_ = bbv.y;
    }
    // issue second half-batch; consume first
#pragma unroll
    for (int j = 0; j < 6; ++j) A1[j] = ap[(6 + j) * 64];
    __builtin_amdgcn_sched_barrier(0);
    f32x4 acc = {};
    __builtin_amdgcn_s_setprio(1);
#pragma unroll
    for (int ks = 0; ks < 6; ++ks)
      acc = __builtin_amdgcn_mfma_f32_16x16x32_f16(A0[ks], B[ks], acc, 0, 0, 0);
    __builtin_amdgcn_s_setprio(0);
    __builtin_amdgcn_sched_barrier(0);   // pin WAR: reload only after consume
    // issue next nt's first half (nt=47 lookahead lands in adjacent ws data,
    // never consumed); consume second half
#pragma unroll
    for (int j = 0; j < 6; ++j) A0[j] = ap[(kKS + j) * 64];
    __builtin_amdgcn_sched_barrier(0);
    __builtin_amdgcn_s_setprio(1);
#pragma unroll
    for (int ks = 0; ks < 6; ++ks)
      acc = __builtin_amdgcn_mfma_f32_16x16x32_f16(A1[ks], B[6 + ks], acc, 0, 0, 0);
    __builtin_amdgcn_s_setprio(0);
    // Gabor activation (lane-local); overlaps the in-flight next-nt loads.
    {
      const float v0 = acc[0] + br_, v1 = acc[1] + bi_;
      const float v2 = acc[2] + cr_, v3 = acc[3] + ci_;
      const float mag = kS2 * (v0 * v0 + v1 * v1 + v2 * v2 + v3 * v3);
      const float amp = __expf(fmaf(-kOmega, v1, -mag));
      const float ph  = kOmega * v0;
      f16x2 pv = {(f16)(amp * __cosf(ph)), (f16)(amp * __sinf(ph))};
      *(f16x2*)(X + xadr(row, q * 4)) = pv;
    }
    if ((nt & 1) == 1) __syncthreads();  // drift-sync: keep 4 waves within the
                                         // 32KB L1 window of the shared A-stream
  }
}

__global__ __launch_bounds__(256, 3)   // ~130 regs -> 3 waves/SIMD, 3 blocks/CU
void wire_main(
    const float* __restrict__ inp, const int* __restrict__ indices,
    const int* __restrict__ model_idx, const int* __restrict__ bias_idx,
    const float* __restrict__ b0a, const float* __restrict__ b0b,
    const float* __restrict__ b1a, const float* __restrict__ b1b,
    const float* __restrict__ b2a, const float* __restrict__ b2b,
    const float* __restrict__ bf, const f16* __restrict__ wsW,
    float* __restrict__ out)
{
  __shared__ __align__(16) char X[kMB * kRowB];   // 49 KB, in-place all layers
  const int d = blockIdx.x;
  const int lg = (d & 7) * 256 + (d >> 3);   // XCD swizzle (2048 % 8 == 0)
  const int c = lg >> 7;                     // 128 blocks per c
  const int n0 = (lg & 127) * kMB;
  const int src = indices[c], m = model_idx[c], bix = bias_idx[c];
  const int tid = threadIdx.x, w = tid >> 6, lane = tid & 63;
  const int kg = lane >> 4, l15 = lane & 15;
  const int row = 16 * w + l15;              // this lane's owned point-row

  // ---- layer 0 as MFMA (C^T): B = own row's coords, A = W0 frags (shared
  // stream across waves); unified Gabor activation with v1=v3=0.
  {
    const float2 xv = *(const float2*)&inp[((size_t)src * kN + n0 + row) * 2];
    f16x8 bx = {};
    if (kg == 0) { bx[0] = (f16)xv.x; bx[1] = (f16)xv.y; }
    const f16x8* w0p = (const f16x8*)(wsW + kW0Off + (size_t)c * kW0Stride);
    const float* b0av = b0a + (size_t)bix * kH;
    const float* b0bv = b0b + (size_t)bix * kH;
#pragma unroll 1
    for (int nt = 0; nt < kNT; ++nt) {
      const int q = nt * 4 + kg;
      const f16x8 a = w0p[nt * 64 + lane];
      f32x4 acc = {};
      acc = __builtin_amdgcn_mfma_f32_16x16x32_f16(a, bx, acc, 0, 0, 0);
      float br_ = 0.f, cr_ = 0.f;
      if (q < kH) { br_ = b0av[q]; cr_ = b0bv[q]; }
      const float v0 = acc[0] + br_;
      const float v2 = acc[2] + cr_;
      const float mag = kS2 * (v0 * v0 + v2 * v2);
      const float amp = __expf(-mag);
      const float ph  = kOmega * v0;
      f16x2 pv = {(f16)(amp * __cosf(ph)), (f16)(amp * __sinf(ph))};
      *(f16x2*)(&X[0] + xadr(row, q * 4)) = pv;
    }
  }
  // rows are wave-private: no inter-layer barriers needed at all.
  hidden_layer(X, (const f16x8*)(wsW + (size_t)(c * 2 + 0) * kWLayerStride),
               b1a + (size_t)bix * kH * 2, b1b + (size_t)bix * kH * 2, w, lane);
  hidden_layer(X, (const f16x8*)(wsW + (size_t)(c * 2 + 1) * kWLayerStride),
               b2a + (size_t)bix * kH * 2, b2b + (size_t)bix * kH * 2, w, lane);
  // ---- final complex 181->3, real part; wave w uses its own rows as A.
  {
    const f16x8* wf = (const f16x8*)(wsW + kWfOff + (size_t)c * kWfStride);
    f32x4 facc = {0.f, 0.f, 0.f, 0.f};
#pragma unroll
    for (int ks = 0; ks < kKS; ++ks) {
      f16x8 a = *(const f16x8*)(&X[0] + xadr(row, ks * 64 + kg * 16));
      f16x8 b = wf[(size_t)ks * 64 + lane];
      facc = __builtin_amdgcn_mfma_f32_16x16x32_f16(a, b, facc, 0, 0, 0);
    }
    if (l15 < kOut) {
      const float bfr = bf[(bix * kOut + l15) * 2];
#pragma unroll
      for (int j = 0; j < 4; ++j) {
        const int orow = w * 16 + kg * 4 + j;
        out[((size_t)c * kN + n0 + orow) * kOut + l15] = facc[j] + bfr;
      }
    }
  }
}

}  // namespace

extern "C" void kernel_launch(void* const* d_in, const int* in_sizes, int n_in,
                              void* d_out, int out_size, void* d_ws, size_t ws_size,
                              hipStream_t stream) {
  const float* inp       = (const float*)d_in[0];
  const int*   indices   = (const int*)  d_in[1];
  const int*   model_idx = (const int*)  d_in[2];
  const int*   bias_idx  = (const int*)  d_in[3];
  const float* W0a = (const float*)d_in[4];
  const float* b0a = (const float*)d_in[5];
  const float* W0b = (const float*)d_in[6];
  const float* b0b = (const float*)d_in[7];
  const float* W1a = (const float*)d_in[8];
  const float* b1a = (const float*)d_in[9];
  const float* W1b = (const float*)d_in[10];
  const float* b1b = (const float*)d_in[11];
  const float* W2a = (const float*)d_in[12];
  const float* b2a = (const float*)d_in[13];
  const float* W2b = (const float*)d_in[14];
  const float* b2b = (const float*)d_in[15];
  const float* Wf  = (const float*)d_in[16];
  const float* bff = (const float*)d_in[17];
  f16*   ws  = (f16*)d_ws;     // needs ~19.9 MB
  float* out = (float*)d_out;

  prep_hidden<<<dim3(kC * 2 * kNT), dim3(768), 0, stream>>>(model_idx, W1a, W1b, W2a, W2b, ws);
  prep_final<<<dim3(kC), dim3(768), 0, stream>>>(model_idx, Wf, ws);
  prep_l0<<<dim3(kC), dim3(256), 0, stream>>>(model_idx, W0a, W0b, ws);
  wire_main<<<dim3(kC * (kN / kMB)), dim3(256), 0, stream>>>(
      inp, indices, model_idx, bias_idx, b0a, b0b,
      b1a, b1b, b2a, b2b, bff, ws, out);
}

// Round 19
// 195.135 us; speedup vs baseline: 1.9510x; 1.9510x over previous
//
#include <hip/hip_runtime.h>

typedef _Float16 f16;
typedef _Float16 f16x2 __attribute__((ext_vector_type(2)));
typedef _Float16 f16x8 __attribute__((ext_vector_type(8)));
typedef float f32x4 __attribute__((ext_vector_type(4)));

namespace {

constexpr int kC = 16, kN = 8192, kH = 181, kOut = 3;
constexpr int kMB = 64;            // points per block (4-tile B-hold)
constexpr int kKpad = 384;         // 12 ksteps * 32
constexpr int kNT = 48;            // tiles of 16 output-comps (4 neurons each)
constexpr int kKS = 12;            // k-steps of 32
constexpr int kRowB = 784;         // 768 data bytes + 16B pad (bank spread)
constexpr float kOmega = 30.f, kS2 = 100.f;

constexpr size_t kWLayerStride = (size_t)kNT * kKS * 64 * 8;  // f16 per (c,layer)
constexpr size_t kWfOff = kWLayerStride * kC * 2;             // f16 elems
constexpr size_t kWfStride = (size_t)kKS * 64 * 8;
constexpr size_t kW0Off = kWfOff + (size_t)kC * kWfStride;    // layer-0 frags
constexpr size_t kW0Stride = (size_t)kNT * 64 * 8;            // per c

__device__ __forceinline__ int xadr(int row, int colb) { return row * kRowB + colb; }

// ---- prep: pack hidden-layer complex weights into fp16 fragment order
// ws[c][L][nt][ks][lane][8]; K rows 2i/2i+1 = (x_re,x_im), 16-wide tile dim =
// 4o+comp. Used as the MFMA *A* operand (C^T formulation).
__global__ __launch_bounds__(768) void prep_hidden(
    const int* __restrict__ model_idx,
    const float* __restrict__ W1a, const float* __restrict__ W1b,
    const float* __restrict__ W2a, const float* __restrict__ W2b,
    f16* __restrict__ ws)
{
  __shared__ float s[kH][2][4][2];   // [i][branch][o_sub][reim]
  const int bid = blockIdx.x;
  const int c  = bid / (2 * kNT);
  const int L  = (bid / kNT) % 2;
  const int nt = bid % kNT;
  const int m  = model_idx[c];
  const float* Wa = (L == 0 ? W1a : W2a) + (size_t)m * kH * kH * 2;
  const float* Wb = (L == 0 ? W1b : W2b) + (size_t)m * kH * kH * 2;
  const int t = threadIdx.x;
  if (t < 2 * kH) {
    const int i = t >> 1, br = t & 1;
    const float* src = (br ? Wb : Wa) + ((size_t)i * kH + nt * 4) * 2;
#pragma unroll
    for (int e = 0; e < 8; ++e) {
      const int osub = e >> 1, reim = e & 1;
      s[i][br][osub][reim] = (nt * 4 + osub < kH) ? src[osub * 2 + reim] : 0.f;
    }
  }
  __syncthreads();
  const int ks = t >> 6, lane = t & 63;
  const int kg = lane >> 4, l15 = lane & 15;
  const int osub = l15 >> 2, comp = l15 & 3, br = comp >> 1;
  const int o = nt * 4 + osub;
  f16x8 v;
#pragma unroll
  for (int j = 0; j < 8; ++j) {
    const int k = ks * 32 + kg * 8 + j;
    float f = 0.f;
    if (k < 2 * kH && o < kH) {
      const int i = k >> 1, kodd = k & 1;
      const int reim = kodd ? (1 - (comp & 1)) : (comp & 1);
      f = s[i][br][osub][reim];
      if (kodd && !(comp & 1)) f = -f;   // -w_im for real-output rows
    }
    v[j] = (f16)f;
  }
  *(f16x8*)&ws[(((size_t)(c * 2 + L) * kNT + nt) * kKS + ks) * 512 + lane * 8] = v;
}

// ---- prep: final layer (real part): col j<3, k=2i -> wf_re, 2i+1 -> -wf_im
__global__ __launch_bounds__(768) void prep_final(
    const int* __restrict__ model_idx, const float* __restrict__ Wf,
    f16* __restrict__ ws)
{
  const int c = blockIdx.x;
  const int m = model_idx[c];
  const int t = threadIdx.x;
  const int ks = t >> 6, lane = t & 63;
  const int kg = lane >> 4, col = lane & 15;
  f16x8 v;
#pragma unroll
  for (int j = 0; j < 8; ++j) {
    const int k = ks * 32 + kg * 8 + j;
    float f = 0.f;
    if (k < 2 * kH && col < kOut) {
      const int i = k >> 1;
      const float* p = &Wf[(((size_t)m * kH + i) * kOut + col) * 2];
      f = (k & 1) ? -p[1] : p[0];
    }
    v[j] = (f16)f;
  }
  *(f16x8*)&ws[kWfOff + ((size_t)c * kKS + ks) * 512 + lane * 8] = v;
}

// ---- prep: layer-0 A-frags. One K=32 tile, only k=0,1 valid.
// comp rows: (W0a[k][o], 0, W0b[k][o], 0) -> acc = (la, 0, lb, 0).
__global__ __launch_bounds__(256) void prep_l0(
    const int* __restrict__ model_idx,
    const float* __restrict__ W0a, const float* __restrict__ W0b,
    f16* __restrict__ ws)
{
  const int c = blockIdx.x;
  const int m = model_idx[c];
#pragma unroll 1
  for (int it = 0; it < 12; ++it) {
    const int slot = it * 256 + threadIdx.x;   // 48 nt x 64 lanes
    const int nt = slot >> 6, lane = slot & 63;
    const int kg = lane >> 4, l15 = lane & 15;
    const int osub = l15 >> 2, comp = l15 & 3;
    const int o = nt * 4 + osub;
    f16x8 v = {};
    if (kg == 0 && o < kH && (comp & 1) == 0) {
#pragma unroll
      for (int k = 0; k < 2; ++k) {
        const float f = (comp == 0) ? W0a[(m * 2 + k) * kH + o]
                                    : W0b[(m * 2 + k) * kH + o];
        v[k] = (f16)f;
      }
    }
    *(f16x8*)&ws[kW0Off + (size_t)c * kW0Stride + (size_t)slot * 8] = v;
  }
}

// ---- one hidden layer, IN PLACE, C^T, P=64, QUARTER-WINDOW A pipeline.
// B-hold 4x12 = 192 frag-regs (AGPR side). A-stream double-buffered in 3-frag
// quarters (A0/A1 = 24 VGPRs — sized so combined regs stay ~340, the same
// 6-waves/CU pool budget r9/r10 proved schedulable; the 48-reg window of
// r13-r15 was what tipped into spilling). Per mi (unroll 1), 4 quarters:
//   Qk: issue next 3 A-frags | 12 MFMAs (3 ks x 4 pt) on the other window
// Each 3-load batch hides under a ~230-cyc MFMA shadow; Q3 prefetches the
// next mi's first quarter (mi=11 lookahead lands in adjacent valid ws data).
// sched_barrier(0) pins load/consume order (r17-validated schedule).
__device__ __forceinline__ void hidden_gemm(
    char* __restrict__ X, const f16x8* __restrict__ wl,
    const float* __restrict__ ba, const float* __restrict__ bb,
    int w, int lane)
{
  const int kg = lane >> 4, l15 = lane & 15;
  f16x8 B[4][kKS];
#pragma unroll
  for (int pt = 0; pt < 4; ++pt)
#pragma unroll
    for (int ks = 0; ks < kKS; ++ks)
      B[pt][ks] = *(const f16x8*)(X + xadr(l15 + 16 * pt, ks * 64 + kg * 16));
  __syncthreads();   // all waves hold X in regs; X may now be overwritten

  f16x8 A0[3], A1[3];
  {  // prologue: first quarter of mi=0
    const f16x8* ap0 = wl + (size_t)(w * 12) * (kKS * 64) + lane;
#pragma unroll
    for (int j = 0; j < 3; ++j) A0[j] = ap0[j * 64];
  }

#pragma unroll 1
  for (int mi = 0; mi < 12; ++mi) {
    const int nt = w * 12 + mi;
    const int q = nt * 4 + kg;           // this lane's neuron
    const f16x8* ap = wl + (size_t)nt * (kKS * 64) + lane;
    f32x4 acc[4] = {};
    // Q0: issue ks3-5, consume A0 = ks0-2
#pragma unroll
    for (int j = 0; j < 3; ++j) A1[j] = ap[(3 + j) * 64];
    __builtin_amdgcn_sched_barrier(0);
    __builtin_amdgcn_s_setprio(1);
#pragma unroll
    for (int ks = 0; ks < 3; ++ks) {
      acc[0] = __builtin_amdgcn_mfma_f32_16x16x32_f16(A0[ks], B[0][ks], acc[0], 0, 0, 0);
      acc[1] = __builtin_amdgcn_mfma_f32_16x16x32_f16(A0[ks], B[1][ks], acc[1], 0, 0, 0);
      acc[2] = __builtin_amdgcn_mfma_f32_16x16x32_f16(A0[ks], B[2][ks], acc[2], 0, 0, 0);
      acc[3] = __builtin_amdgcn_mfma_f32_16x16x32_f16(A0[ks], B[3][ks], acc[3], 0, 0, 0);
    }
    __builtin_amdgcn_s_setprio(0);
    __builtin_amdgcn_sched_barrier(0);
    // Q1: issue ks6-8, consume A1 = ks3-5
#pragma unroll
    for (int j = 0; j < 3; ++j) A0[j] = ap[(6 + j) * 64];
    __builtin_amdgcn_sched_barrier(0);
    __builtin_amdgcn_s_setprio(1);
#pragma unroll
    for (int ks = 0; ks < 3; ++ks) {
      acc[0] = __builtin_amdgcn_mfma_f32_16x16x32_f16(A1[ks], B[0][3 + ks], acc[0], 0, 0, 0);
      acc[1] = __builtin_amdgcn_mfma_f32_16x16x32_f16(A1[ks], B[1][3 + ks], acc[1], 0, 0, 0);
      acc[2] = __builtin_amdgcn_mfma_f32_16x16x32_f16(A1[ks], B[2][3 + ks], acc[2], 0, 0, 0);
      acc[3] = __builtin_amdgcn_mfma_f32_16x16x32_f16(A1[ks], B[3][3 + ks], acc[3], 0, 0, 0);
    }
    __builtin_amdgcn_s_setprio(0);
    __builtin_amdgcn_sched_barrier(0);
    // Q2: issue ks9-11, consume A0 = ks6-8
#pragma unroll
    for (int j = 0; j < 3; ++j) A1[j] = ap[(9 + j) * 64];
    __builtin_amdgcn_sched_barrier(0);
    __builtin_amdgcn_s_setprio(1);
#pragma unroll
    for (int ks = 0; ks < 3; ++ks) {
      acc[0] = __builtin_amdgcn_mfma_f32_16x16x32_f16(A0[ks], B[0][6 + ks], acc[0], 0, 0, 0);
      acc[1] = __builtin_amdgcn_mfma_f32_16x16x32_f16(A0[ks], B[1][6 + ks], acc[1], 0, 0, 0);
      acc[2] = __builtin_amdgcn_mfma_f32_16x16x32_f16(A0[ks], B[2][6 + ks], acc[2], 0, 0, 0);
      acc[3] = __builtin_amdgcn_mfma_f32_16x16x32_f16(A0[ks], B[3][6 + ks], acc[3], 0, 0, 0);
    }
    __builtin_amdgcn_s_setprio(0);
    __builtin_amdgcn_sched_barrier(0);
    // Q3: issue next-mi ks0-2, consume A1 = ks9-11
#pragma unroll
    for (int j = 0; j < 3; ++j) A0[j] = ap[(kKS + j) * 64];
    __builtin_amdgcn_sched_barrier(0);
    __builtin_amdgcn_s_setprio(1);
#pragma unroll
    for (int ks = 0; ks < 3; ++ks) {
      acc[0] = __builtin_amdgcn_mfma_f32_16x16x32_f16(A1[ks], B[0][9 + ks], acc[0], 0, 0, 0);
      acc[1] = __builtin_amdgcn_mfma_f32_16x16x32_f16(A1[ks], B[1][9 + ks], acc[1], 0, 0, 0);
      acc[2] = __builtin_amdgcn_mfma_f32_16x16x32_f16(A1[ks], B[2][9 + ks], acc[2], 0, 0, 0);
      acc[3] = __builtin_amdgcn_mfma_f32_16x16x32_f16(A1[ks], B[3][9 + ks], acc[3], 0, 0, 0);
    }
    __builtin_amdgcn_s_setprio(0);
    // bias (post-loop, short live range) + lane-local Gabor activation;
    // overlaps the in-flight next-mi quarter.
    float br_ = 0.f, bi_ = 0.f, cr_ = 0.f, ci_ = 0.f;
    if (q < kH) {
      const float2 bav = *(const float2*)&ba[q * 2];
      const float2 bbv = *(const float2*)&bb[q * 2];
      br_ = bav.x; bi_ = bav.y; cr_ = bbv.x; ci_ = bbv.y;
    }
#pragma unroll
    for (int pt = 0; pt < 4; ++pt) {
      const float v0 = acc[pt][0] + br_, v1 = acc[pt][1] + bi_;
      const float v2 = acc[pt][2] + cr_, v3 = acc[pt][3] + ci_;
      const float mag = kS2 * (v0 * v0 + v1 * v1 + v2 * v2 + v3 * v3);
      const float amp = __expf(fmaf(-kOmega, v1, -mag));
      const float ph  = kOmega * v0;
      f16x2 pv = {(f16)(amp * __cosf(ph)), (f16)(amp * __sinf(ph))};
      *(f16x2*)(X + xadr(l15 + 16 * pt, q * 4)) = pv;
    }
  }
}

__global__ __launch_bounds__(256, 2)   // B 192 (AGPR) + windows 24 + acc 16
void wire_main(
    const float* __restrict__ inp, const int* __restrict__ indices,
    const int* __restrict__ model_idx, const int* __restrict__ bias_idx,
    const float* __restrict__ b0a, const float* __restrict__ b0b,
    const float* __restrict__ b1a, const float* __restrict__ b1b,
    const float* __restrict__ b2a, const float* __restrict__ b2b,
    const float* __restrict__ bf, const f16* __restrict__ wsW,
    float* __restrict__ out)
{
  __shared__ __align__(16) char X[kMB * kRowB];   // 49 KB single buffer
  const int d = blockIdx.x;
  const int lg = (d & 7) * 256 + (d >> 3);   // XCD swizzle (2048 % 8 == 0)
  const int c = lg >> 7;                     // 128 blocks per c
  const int n0 = (lg & 127) * kMB;
  const int src = indices[c], m = model_idx[c], bix = bias_idx[c];
  const int tid = threadIdx.x, w = tid >> 6, lane = tid & 63;
  const int kg = lane >> 4, l15 = lane & 15;

  // ---- layer 0 as MFMA (C^T): B = input coords (k=0,1 of one K-tile),
  // A = packed W0 frags; unified Gabor activation with v1=v3=0.
  {
    f16x8 Bx[4];
#pragma unroll
    for (int pt = 0; pt < 4; ++pt) {
      const int row = l15 + 16 * pt;
      const float2 xv = *(const float2*)&inp[((size_t)src * kN + n0 + row) * 2];
      f16x8 b = {};
      if (kg == 0) { b[0] = (f16)xv.x; b[1] = (f16)xv.y; }
      Bx[pt] = b;
    }
    const f16x8* w0p = (const f16x8*)(wsW + kW0Off + (size_t)c * kW0Stride);
    const float* b0av = b0a + (size_t)bix * kH;
    const float* b0bv = b0b + (size_t)bix * kH;
#pragma unroll 1
    for (int mi = 0; mi < 12; ++mi) {
      const int nt = w * 12 + mi;
      const int q = nt * 4 + kg;
      const f16x8 a = w0p[nt * 64 + lane];
      f32x4 acc[4] = {};
      __builtin_amdgcn_s_setprio(1);
      acc[0] = __builtin_amdgcn_mfma_f32_16x16x32_f16(a, Bx[0], acc[0], 0, 0, 0);
      acc[1] = __builtin_amdgcn_mfma_f32_16x16x32_f16(a, Bx[1], acc[1], 0, 0, 0);
      acc[2] = __builtin_amdgcn_mfma_f32_16x16x32_f16(a, Bx[2], acc[2], 0, 0, 0);
      acc[3] = __builtin_amdgcn_mfma_f32_16x16x32_f16(a, Bx[3], acc[3], 0, 0, 0);
      __builtin_amdgcn_s_setprio(0);
      float br_ = 0.f, cr_ = 0.f;
      if (q < kH) { br_ = b0av[q]; cr_ = b0bv[q]; }
#pragma unroll
      for (int pt = 0; pt < 4; ++pt) {
        const float v0 = acc[pt][0] + br_;
        const float v2 = acc[pt][2] + cr_;
        const float mag = kS2 * (v0 * v0 + v2 * v2);
        const float amp = __expf(-mag);
        const float ph  = kOmega * v0;
        f16x2 pv = {(f16)(amp * __cosf(ph)), (f16)(amp * __sinf(ph))};
        *(f16x2*)(&X[0] + xadr(l15 + 16 * pt, q * 4)) = pv;
      }
    }
  }
  __syncthreads();
  hidden_gemm(X, (const f16x8*)(wsW + (size_t)(c * 2 + 0) * kWLayerStride),
              b1a + (size_t)bix * kH * 2, b1b + (size_t)bix * kH * 2, w, lane);
  __syncthreads();
  hidden_gemm(X, (const f16x8*)(wsW + (size_t)(c * 2 + 1) * kWLayerStride),
              b2a + (size_t)bix * kH * 2, b2b + (size_t)bix * kH * 2, w, lane);
  __syncthreads();
  // ---- final complex 181->3, real part; wave w owns point-tile w
  {
    const f16x8* wf = (const f16x8*)(wsW + kWfOff + (size_t)c * kWfStride);
    f32x4 facc = {0.f, 0.f, 0.f, 0.f};
#pragma unroll
    for (int ks = 0; ks < kKS; ++ks) {
      f16x8 a = *(const f16x8*)(&X[0] + xadr(l15 + 16 * w, ks * 64 + kg * 16));
      f16x8 b = wf[(size_t)ks * 64 + lane];
      facc = __builtin_amdgcn_mfma_f32_16x16x32_f16(a, b, facc, 0, 0, 0);
    }
    if (l15 < kOut) {
      const float bfr = bf[(bix * kOut + l15) * 2];
#pragma unroll
      for (int j = 0; j < 4; ++j) {
        const int row = w * 16 + kg * 4 + j;
        out[((size_t)c * kN + n0 + row) * kOut + l15] = facc[j] + bfr;
      }
    }
  }
}

}  // namespace

extern "C" void kernel_launch(void* const* d_in, const int* in_sizes, int n_in,
                              void* d_out, int out_size, void* d_ws, size_t ws_size,
                              hipStream_t stream) {
  const float* inp       = (const float*)d_in[0];
  const int*   indices   = (const int*)  d_in[1];
  const int*   model_idx = (const int*)  d_in[2];
  const int*   bias_idx  = (const int*)  d_in[3];
  const float* W0a = (const float*)d_in[4];
  const float* b0a = (const float*)d_in[5];
  const float* W0b = (const float*)d_in[6];
  const float* b0b = (const float*)d_in[7];
  const float* W1a = (const float*)d_in[8];
  const float* b1a = (const float*)d_in[9];
  const float* W1b = (const float*)d_in[10];
  const float* b1b = (const float*)d_in[11];
  const float* W2a = (const float*)d_in[12];
  const float* b2a = (const float*)d_in[13];
  const float* W2b = (const float*)d_in[14];
  const float* b2b = (const float*)d_in[15];
  const float* Wf  = (const float*)d_in[16];
  const float* bff = (const float*)d_in[17];
  f16*   ws  = (f16*)d_ws;     // needs ~19.9 MB
  float* out = (float*)d_out;

  prep_hidden<<<dim3(kC * 2 * kNT), dim3(768), 0, stream>>>(model_idx, W1a, W1b, W2a, W2b, ws);
  prep_final<<<dim3(kC), dim3(768), 0, stream>>>(model_idx, Wf, ws);
  prep_l0<<<dim3(kC), dim3(256), 0, stream>>>(model_idx, W0a, W0b, ws);
  wire_main<<<dim3(kC * (kN / kMB)), dim3(256), 0, stream>>>(
      inp, indices, model_idx, bias_idx, b0a, b0b,
      b1a, b1b, b2a, b2b, bff, ws, out);
}